// Round 7
// baseline (386.546 us; speedup 1.0000x reference)
//
#include <hip/hip_runtime.h>

typedef unsigned short u16;
typedef __bf16 bf16x8 __attribute__((ext_vector_type(8)));
typedef float f32x4 __attribute__((ext_vector_type(4)));

#define B_ 2
#define T_ 1024
#define D_ 1024
#define H_ 64
#define HS_ 64
#define FF_ 4096
#define SZ_QKV 8388608L
// softmax in exp2 domain: scale = (1/sqrt(64)) * log2(e); folded into Q staging
#define S_SCALE 0.1803368801111f

__device__ __forceinline__ float bf2f(u16 u) {
  union { unsigned int v; float f; } x; x.v = ((unsigned int)u) << 16; return x.f;
}
__device__ __forceinline__ u16 f2bf(float f) {
  union { float f; unsigned int v; } x; x.f = f;
  unsigned int r = x.v + 0x7fffu + ((x.v >> 16) & 1u);
  return (u16)(r >> 16);
}
__device__ __forceinline__ u16 f2bf_rtz(float f) {
  union { float f; unsigned int v; } x; x.f = f;
  return (u16)(x.v >> 16);
}

typedef __attribute__((address_space(3))) unsigned int lds_u32;
typedef __attribute__((address_space(1))) const unsigned int glb_u32;
__device__ __forceinline__ void gload_lds16(const void* g, void* l) {
  __builtin_amdgcn_global_load_lds((glb_u32*)g, (lds_u32*)l, 16, 0, 0);
}

// ---------------------------------------------------------------------------
// Consolidated pre-pass: x cvt + all weight transpose/convert (+Wo row perm).
__global__ __launch_bounds__(256) void prep(
    const float* __restrict__ x, const float* __restrict__ Wq,
    const float* __restrict__ Wk, const float* __restrict__ Wv,
    const float* __restrict__ Wo, const float* __restrict__ W1,
    const float* __restrict__ W2,
    u16* __restrict__ xb, u16* __restrict__ Wqkvt, u16* __restrict__ Wot,
    u16* __restrict__ W1t, u16* __restrict__ W2t)
{
  __shared__ float tile[64][65];
  int id = blockIdx.x;
  if (id < 1024) {           // x: fp32 -> bf16
    const long i = ((long)id * 256 + threadIdx.x) * 8;
    float4 a = *(const float4*)(x + i);
    float4 b = *(const float4*)(x + i + 4);
    union { uint4 v; u16 u[8]; } o;
    o.u[0]=f2bf(a.x); o.u[1]=f2bf(a.y); o.u[2]=f2bf(a.z); o.u[3]=f2bf(a.w);
    o.u[4]=f2bf(b.x); o.u[5]=f2bf(b.y); o.u[6]=f2bf(b.z); o.u[7]=f2bf(b.w);
    *(uint4*)(xb + i) = o.v;
    return;
  }
  id -= 1024;
  const float* in; u16* out; long ibase, obase; int in_rs, out_rs, r0, c0;
  if (id < 3072) {           // Wq/Wk/Wv: [64][1024][64] -> [w*4096+z*64+c][r]
    const int w = id >> 10, rem = id & 1023;
    const int z = rem >> 4, rt = rem & 15;
    in = (w == 0) ? Wq : (w == 1) ? Wk : Wv;
    ibase = (long)z * 65536; in_rs = 64; r0 = rt * 64; c0 = 0;
    out = Wqkvt + (long)w * 4194304;
    obase = (long)z * 65536; out_rs = 1024;
  } else if (id < 4096) {    // Wo row-permuted: Wot'[c][h*64+e] = Wo[e*64+h][c]
    const int rem = id - 3072;
    const int z = rem >> 4, ct = rem & 15;      // z = h
    in = Wo; ibase = (long)z * 1024; in_rs = 65536; r0 = 0; c0 = ct * 64;
    out = Wot; obase = (long)z * 64; out_rs = 4096;
  } else if (id < 5120) {    // W1 [1024][4096] -> W1t[c][r]
    const int rem = id - 4096;
    const int rt = rem >> 6, ct = rem & 63;
    in = W1; ibase = 0; in_rs = 4096; r0 = rt * 64; c0 = ct * 64;
    out = W1t; obase = 0; out_rs = 1024;
  } else {                   // W2 [4096][1024] -> W2t[c][r]
    const int rem = id - 5120;
    const int rt = rem >> 4, ct = rem & 15;
    in = W2; ibase = 0; in_rs = 1024; r0 = rt * 64; c0 = ct * 64;
    out = W2t; obase = 0; out_rs = 4096;
  }
  const int t = threadIdx.x, lr = t >> 4, lc4 = (t & 15) * 4;
  #pragma unroll
  for (int j = 0; j < 4; ++j) {
    float4 f = *(const float4*)(in + ibase + (long)(r0 + lr + j * 16) * in_rs + c0 + lc4);
    tile[lr + j * 16][lc4]     = f.x;
    tile[lr + j * 16][lc4 + 1] = f.y;
    tile[lr + j * 16][lc4 + 2] = f.z;
    tile[lr + j * 16][lc4 + 3] = f.w;
  }
  __syncthreads();
  const int cr = t >> 3, ch = t & 7;
  #pragma unroll
  for (int j2 = 0; j2 < 2; ++j2) {
    const int crr = cr + j2 * 32;
    union { uint4 v; u16 u[8]; } o;
    #pragma unroll
    for (int i = 0; i < 8; ++i) o.u[i] = f2bf(tile[ch * 8 + i][crr]);
    *(uint4*)(out + obase + (long)(c0 + crr) * out_rs + r0 + ch * 8) = o.v;
  }
}

// ---------------------------------------------------------------------------
// m97-style bf16 GEMM: C[M,N] = A[M,K-slice] @ Bt[N,K-slice]^T. BK=32, TN=128.
// GRIDSWAP=1: bn = blockIdx.x (XCD = bn%8 -> per-XCD B-tile residency).
// EPI: 1 bias+relu->bf16 (LDS full-line epi), 2 QKV scatter (LDS full-line
// epi), 3 fp32 split-K partial (direct, line-aligned per quad).
template<int TM, int EPI, int GRIDSWAP>
__global__ __launch_bounds__(256) void gemm_k(
    const u16* __restrict__ A, const u16* __restrict__ Bt, u16* __restrict__ C,
    const float* __restrict__ bias, int K, int lda, int ldb, int koff, int ldc)
{
  constexpr int NR = (TM == 128) ? 4 : 2;
  constexpr int AIT = TM / 64;
  __shared__ __attribute__((aligned(16))) u16 As[TM * 32];
  __shared__ __attribute__((aligned(16))) u16 Bs[128 * 32];
  __shared__ __attribute__((aligned(16))) u16 Es[4][16][72];   // epilogue transit
  const int bm = GRIDSWAP ? blockIdx.y : blockIdx.x;
  const int bn = GRIDSWAP ? blockIdx.x : blockIdx.y;
  const int bz = blockIdx.z;
  const long ko = (long)bz * koff;
  const int tid = threadIdx.x, wave = tid >> 6, lane = tid & 63;
  const int quad = lane >> 4, l16 = lane & 15;
  const int wm = (TM == 128) ? (wave & 1) * 64 : 0;
  const int wn = (TM == 128) ? (wave >> 1) * 64 : wave * 32;

  f32x4 acc[4][NR];
  #pragma unroll
  for (int i = 0; i < 4; ++i)
    #pragma unroll
    for (int j = 0; j < NR; ++j) acc[i][j] = (f32x4){0, 0, 0, 0};

  const int nK = K >> 5;
  for (int kc = 0; kc < nK; ++kc) {
    const int k0 = kc << 5;
    #pragma unroll
    for (int jA = 0; jA < AIT; ++jA) {
      const int i = jA * 4 + wave;
      const int chunk = i * 64 + lane;
      gload_lds16(A + (long)(bm * TM + (chunk >> 2)) * lda + ko + k0 + (chunk & 3) * 8,
                  (u16*)As + i * 512);
    }
    #pragma unroll
    for (int jB = 0; jB < 2; ++jB) {
      const int i = jB * 4 + wave;
      const int chunk = i * 64 + lane;
      gload_lds16(Bt + (long)(bn * 128 + (chunk >> 2)) * ldb + ko + k0 + (chunk & 3) * 8,
                  (u16*)Bs + i * 512);
    }
    __syncthreads();
    bf16x8 a[4], b[NR];
    #pragma unroll
    for (int i = 0; i < 4; ++i)
      a[i] = *(const bf16x8*)&As[(wm + i * 16 + l16) * 32 + quad * 8];
    #pragma unroll
    for (int j = 0; j < NR; ++j)
      b[j] = *(const bf16x8*)&Bs[(wn + j * 16 + l16) * 32 + quad * 8];
    #pragma unroll
    for (int i = 0; i < 4; ++i)
      #pragma unroll
      for (int j = 0; j < NR; ++j)
        acc[i][j] = __builtin_amdgcn_mfma_f32_16x16x32_bf16(a[i], b[j], acc[i][j], 0, 0, 0);
    __syncthreads();
  }

  if (EPI == 3) {
    // direct fp32 partial stores (quad covers 64B line)
    #pragma unroll
    for (int j = 0; j < NR; ++j) {
      const int col = bn * 128 + wn + j * 16 + l16;
      #pragma unroll
      for (int i = 0; i < 4; ++i)
        #pragma unroll
        for (int r = 0; r < 4; ++r) {
          const int row = bm * TM + wm + i * 16 + quad * 4 + r;
          ((float*)C)[(long)bz * 2097152 + (long)row * ldc + col] = acc[i][j][r];
        }
    }
  } else {
    // EPI 1/2 (TM=128): LDS transit -> 16B/lane full-line stores
    const int colbase = bn * 128 + wn;
    float bv[NR];
    #pragma unroll
    for (int j = 0; j < NR; ++j) bv[j] = (EPI == 1) ? bias[colbase + j * 16 + l16] : 0.f;
    const int rr = lane >> 2, ck = lane & 3;
    const int which = colbase >> 12, hh = (colbase >> 6) & 63;
    #pragma unroll
    for (int i = 0; i < 4; ++i) {
      #pragma unroll
      for (int j = 0; j < NR; ++j)
        #pragma unroll
        for (int r = 0; r < 4; ++r) {
          float vv = acc[i][j][r] + bv[j];
          if (EPI == 1) vv = fmaxf(vv, 0.f);
          Es[wave][quad * 4 + r][j * 16 + l16] = f2bf(vv);
        }
      // wave-private slice: compiler inserts lgkmcnt wait, no barrier needed
      const int row = bm * TM + wm + i * 16 + rr;
      uint4 w0 = *(const uint4*)&Es[wave][rr][ck * 8];
      uint4 w1 = *(const uint4*)&Es[wave][rr][32 + ck * 8];
      if (EPI == 2) {
        const int bb = row >> 10, tt = row & 1023;
        u16* dst = C + (long)which * SZ_QKV + ((long)(bb * 64 + hh)) * 65536L + tt * 64;
        *(uint4*)(dst + ck * 8) = w0;
        *(uint4*)(dst + 32 + ck * 8) = w1;
      } else {
        u16* dst = C + (long)row * ldc + colbase;
        *(uint4*)(dst + ck * 8) = w0;
        *(uint4*)(dst + 32 + ck * 8) = w1;
      }
    }
  }
}

// ---------------------------------------------------------------------------
// Flash causal attention, no-max variant. Grid (B*H, 16). Block 256 (4 waves).
// Output HEAD-MAJOR: Om[b*T + t][h*64 + e].
__global__ __launch_bounds__(256) void attn_flash(
    const u16* __restrict__ Q, const u16* __restrict__ Kg,
    const u16* __restrict__ V, u16* __restrict__ Om)
{
  __shared__ __attribute__((aligned(16))) u16 Ks[2][64][72];
  __shared__ __attribute__((aligned(16))) u16 Vs[2][64][72];
  __shared__ __attribute__((aligned(16))) u16 QP[4][16][72];
  const int bh = blockIdx.x;
  const int qt = gridDim.y - 1 - blockIdx.y;   // longest first
  const int b = bh >> 6, h = bh & 63;
  const long base = (long)bh * (T_ * HS_);
  const int tid = threadIdx.x;
  const int wave = tid >> 6, lane = tid & 63, quad = lane >> 4, l16 = lane & 15;
  const int sm = tid >> 2, sc = (tid & 3) * 16;
  const int vswz = (sc >> 4) << 3;             // Vs column swizzle for writes

  {
    const int qr = lane >> 3, qe = (lane & 7) * 8;
    #pragma unroll
    for (int j = 0; j < 2; ++j) {
      union { uint4 v; u16 u[8]; } a, o;
      a.v = *(const uint4*)(Q + base + (long)(qt * 64 + wave * 16 + qr + j * 8) * HS_ + qe);
      #pragma unroll
      for (int i = 0; i < 8; ++i) o.u[i] = f2bf(bf2f(a.u[i]) * S_SCALE);
      *(uint4*)&QP[wave][qr + j * 8][qe] = o.v;
    }
  }
  bf16x8 aq0 = *(const bf16x8*)&QP[wave][l16][quad * 8];
  bf16x8 aq1 = *(const bf16x8*)&QP[wave][l16][32 + quad * 8];

  float psum[4] = { 0.f, 0.f, 0.f, 0.f };
  f32x4 oacc[4] = { {0,0,0,0}, {0,0,0,0}, {0,0,0,0}, {0,0,0,0} };

  uint4 kA, kB, vA, vB;
  kA = *(const uint4*)(Kg + base + (long)sm * HS_ + sc);
  kB = *(const uint4*)(Kg + base + (long)sm * HS_ + sc + 8);
  vA = *(const uint4*)(V  + base + (long)sm * HS_ + sc);
  vB = *(const uint4*)(V  + base + (long)sm * HS_ + sc + 8);
  {
    *(uint4*)&Ks[0][sm][sc] = kA; *(uint4*)&Ks[0][sm][sc + 8] = kB;
    union { uint4 v; u16 u[8]; } t0, t1; t0.v = vA; t1.v = vB;
    #pragma unroll
    for (int i = 0; i < 8; ++i) Vs[0][sc + i][sm ^ vswz] = t0.u[i];
    #pragma unroll
    for (int i = 0; i < 8; ++i) Vs[0][sc + 8 + i][sm ^ vswz] = t1.u[i];
  }
  __syncthreads();

  for (int kt = 0; kt <= qt; ++kt) {
    const int cur = kt & 1;
    const bool pf = (kt < qt);
    if (pf) {
      const long nb = base + (long)((kt + 1) * 64 + sm) * HS_ + sc;
      kA = *(const uint4*)(Kg + nb); kB = *(const uint4*)(Kg + nb + 8);
      vA = *(const uint4*)(V  + nb); vB = *(const uint4*)(V  + nb + 8);
    }

    f32x4 sacc[4] = { {0,0,0,0}, {0,0,0,0}, {0,0,0,0}, {0,0,0,0} };
    #pragma unroll
    for (int nt = 0; nt < 4; ++nt) {
      bf16x8 b0 = *(const bf16x8*)&Ks[cur][nt * 16 + l16][quad * 8];
      bf16x8 b1 = *(const bf16x8*)&Ks[cur][nt * 16 + l16][32 + quad * 8];
      sacc[nt] = __builtin_amdgcn_mfma_f32_16x16x32_bf16(aq0, b0, sacc[nt], 0, 0, 0);
      sacc[nt] = __builtin_amdgcn_mfma_f32_16x16x32_bf16(aq1, b1, sacc[nt], 0, 0, 0);
    }

    if (kt == qt) {
      #pragma unroll
      for (int nt = 0; nt < 4; ++nt) {
        const int col = nt * 16 + l16;
        #pragma unroll
        for (int r = 0; r < 4; ++r) {
          const int row = wave * 16 + quad * 4 + r;
          float p = exp2f(sacc[nt][r]);
          p = (col <= row) ? p : 0.f;
          sacc[nt][r] = p; psum[r] += p;
        }
      }
    } else {
      #pragma unroll
      for (int nt = 0; nt < 4; ++nt)
        #pragma unroll
        for (int r = 0; r < 4; ++r) {
          const float p = exp2f(sacc[nt][r]);
          sacc[nt][r] = p; psum[r] += p;
        }
    }

    #pragma unroll
    for (int nt = 0; nt < 4; ++nt)
      #pragma unroll
      for (int r = 0; r < 4; ++r)
        QP[wave][quad * 4 + r][nt * 16 + l16] = f2bf_rtz(sacc[nt][r]);
    bf16x8 p0 = *(const bf16x8*)&QP[wave][l16][quad * 8];
    bf16x8 p1 = *(const bf16x8*)&QP[wave][l16][32 + quad * 8];

    #pragma unroll
    for (int et = 0; et < 4; ++et) {
      const int c0 = ((quad ^ et) * 8);
      bf16x8 b0 = *(const bf16x8*)&Vs[cur][et * 16 + l16][c0];
      bf16x8 b1 = *(const bf16x8*)&Vs[cur][et * 16 + l16][32 + c0];
      oacc[et] = __builtin_amdgcn_mfma_f32_16x16x32_bf16(p0, b0, oacc[et], 0, 0, 0);
      oacc[et] = __builtin_amdgcn_mfma_f32_16x16x32_bf16(p1, b1, oacc[et], 0, 0, 0);
    }

    if (pf) {
      const int nxt = 1 - cur;
      *(uint4*)&Ks[nxt][sm][sc] = kA; *(uint4*)&Ks[nxt][sm][sc + 8] = kB;
      union { uint4 v; u16 u[8]; } t0, t1; t0.v = vA; t1.v = vB;
      #pragma unroll
      for (int i = 0; i < 8; ++i) Vs[nxt][sc + i][sm ^ vswz] = t0.u[i];
      #pragma unroll
      for (int i = 0; i < 8; ++i) Vs[nxt][sc + 8 + i][sm ^ vswz] = t1.u[i];
    }
    __syncthreads();
  }

  #pragma unroll
  for (int off = 1; off < 16; off <<= 1)
    #pragma unroll
    for (int r = 0; r < 4; ++r)
      psum[r] += __shfl_xor(psum[r], off, 64);
  u16 (*Os)[72] = Ks[0];
  #pragma unroll
  for (int r = 0; r < 4; ++r) {
    const float rinv = 1.f / fmaxf(psum[r], 1e-20f);
    const int row = wave * 16 + quad * 4 + r;
    #pragma unroll
    for (int et = 0; et < 4; ++et)
      Os[row][et * 16 + l16] = f2bf(oacc[et][r] * rinv);
  }
  const int orow = wave * 16 + (lane >> 3), oe = (lane & 7) * 8;
  #pragma unroll
  for (int it = 0; it < 2; ++it) {
    const int rr = orow + it * 8;
    uint4 o = *(const uint4*)&Os[rr][oe];
    *(uint4*)(Om + ((long)(b * T_ + qt * 64 + rr)) * 4096 + h * 64 + oe) = o;
  }
}

// ---------------------------------------------------------------------------
// out[row] = LN(X[row] + bias + sum_p P4[p][row]) * g + be
template<int XBF, int OBF>
__global__ __launch_bounds__(256) void ln_sum4(
    const float* __restrict__ P4, const float* __restrict__ bias,
    const void* __restrict__ Xv, const float* __restrict__ g,
    const float* __restrict__ be, void* __restrict__ outv)
{
  __shared__ float red[8];
  const int row = blockIdx.x, tid = threadIdx.x;
  const long base = (long)row * D_;
  float v4[4]; float s = 0.f;
  #pragma unroll
  for (int j = 0; j < 4; ++j) {
    const int i = tid + j * 256;
    float acc = bias[i];
    #pragma unroll
    for (int p = 0; p < 4; ++p) acc += P4[(long)p * 2097152 + base + i];
    const float xval = XBF ? bf2f(((const u16*)Xv)[base + i]) : ((const float*)Xv)[base + i];
    v4[j] = xval + acc;
    s += v4[j];
  }
  #pragma unroll
  for (int off = 32; off > 0; off >>= 1) s += __shfl_down(s, off, 64);
  if ((tid & 63) == 0) red[tid >> 6] = s;
  __syncthreads();
  const float mu = (red[0] + red[1] + red[2] + red[3]) * (1.f / D_);
  float vs = 0.f;
  #pragma unroll
  for (int j = 0; j < 4; ++j) { const float d = v4[j] - mu; vs += d * d; }
  #pragma unroll
  for (int off = 32; off > 0; off >>= 1) vs += __shfl_down(vs, off, 64);
  __syncthreads();
  if ((tid & 63) == 0) red[tid >> 6] = vs;
  __syncthreads();
  const float rs = rsqrtf((red[0] + red[1] + red[2] + red[3]) * (1.f / D_) + 1e-5f);
  #pragma unroll
  for (int j = 0; j < 4; ++j) {
    const int i = tid + j * 256;
    const float o = (v4[j] - mu) * rs * g[i] + be[i];
    if (OBF) ((u16*)outv)[base + i] = f2bf(o);
    else     ((float*)outv)[base + i] = o;
  }
}

// ---------------------------------------------------------------------------
extern "C" void kernel_launch(void* const* d_in, const int* in_sizes, int n_in,
                              void* d_out, int out_size, void* d_ws, size_t ws_size,
                              hipStream_t stream) {
  const float* x   = (const float*)d_in[0];
  const float* Wq  = (const float*)d_in[1];
  const float* Wk  = (const float*)d_in[2];
  const float* Wv  = (const float*)d_in[3];
  const float* Wo  = (const float*)d_in[4];
  const float* bo  = (const float*)d_in[5];
  const float* W1  = (const float*)d_in[6];
  const float* b1  = (const float*)d_in[7];
  const float* W2  = (const float*)d_in[8];
  const float* b2  = (const float*)d_in[9];
  const float* g1  = (const float*)d_in[10];
  const float* be1 = (const float*)d_in[11];
  const float* g2  = (const float*)d_in[12];
  const float* be2 = (const float*)d_in[13];
  float* out = (float*)d_out;

  u16* ws = (u16*)d_ws;
  u16* xb    = ws;                    // 2,097,152 u16
  u16* Wqkvt = xb + 2097152;          // 12,582,912
  u16* Wot   = Wqkvt + 12582912;      // 4,194,304 (row-permuted: [col][h*64+e])
  u16* W1t   = Wot + 4194304;         // 4,194,304
  u16* W2t   = W1t + 4194304;         // 4,194,304
  u16* q     = W2t + 4194304;         // 8,388,608  [bh][t][e]
  u16* k     = q + SZ_QKV;
  u16* v     = k + SZ_QKV;
  u16* Om    = v + SZ_QKV;            // 8,388,608  [b*T+t][h*64+e]
  float* P1 = (float*)q;              // split-K partials over q+k
  float* P2 = (float*)q;
  u16* x1  = v;
  u16* h1  = Om;

  dim3 blk(256);

  // single consolidated pre-pass
  prep<<<dim3(7168), blk, 0, stream>>>(x, Wq, Wk, Wv, Wo, W1, W2,
                                       xb, Wqkvt, Wot, W1t, W2t);

  // QKV: [2048,1024]@[1024,12288] -> scatter q/k/v [bh][t][e]
  // GRIDSWAP: bn on x -> XCD = bn%8, per-XCD B residency (3 MB)
  gemm_k<128, 2, 1><<<dim3(96, 16), blk, 0, stream>>>(
      xb, Wqkvt, q, nullptr, 1024, 1024, 1024, 0, 0);

  // causal flash attention -> Om (head-major)
  attn_flash<<<dim3(128, 16), blk, 0, stream>>>(q, k, v, Om);

  // out projection, split-K=4 (A-localized orientation: bm on x)
  gemm_k<64, 3, 0><<<dim3(32, 8, 4), blk, 0, stream>>>(
      Om, Wot, (u16*)P1, nullptr, 1024, 4096, 4096, 1024, 1024);

  // x1 = LN(x + (sum partials + bo))
  ln_sum4<0, 1><<<dim3(2048), blk, 0, stream>>>(P1, bo, x, g1, be1, x1);

  // FF1: relu([2048,1024]@[1024,4096] + b1), GRIDSWAP
  gemm_k<128, 1, 1><<<dim3(32, 16), blk, 0, stream>>>(
      x1, W1t, h1, b1, 1024, 1024, 1024, 0, 4096);

  // FF2, split-K=4
  gemm_k<64, 3, 0><<<dim3(32, 8, 4), blk, 0, stream>>>(
      h1, W2t, (u16*)P2, nullptr, 1024, 4096, 4096, 1024, 1024);

  // out = LN(x1 + (sum partials + b2))
  ln_sum4<1, 0><<<dim3(2048), blk, 0, stream>>>(P2, b2, x1, g2, be2, out);

  (void)in_sizes; (void)n_in; (void)out_size; (void)ws_size;
}